// Round 13
// baseline (4749.973 us; speedup 1.0000x reference)
//
#include <hip/hip_runtime.h>
#include <math.h>

// ODE-RNN forward: B=1024, T=100, D=32, H=256, MID=50 (pad 52), RK4x4.
// Round 13: WAVE-FUSED eval. Block = 4 waves = 4 rows; wave w runs row w's
// entire RK4 chain alone (L1: w1 in 208 VGPRs + red16; L2: w2/mid/yc via
// intra-wave LDS bounce -> lgkmcnt only, NO barriers). Barriers 38 -> 4/step.
// waves_per_eu(1) lifts VGPR cap to 512 (need ~300). yct XOR-swizzled
// (phys(a) = (a&3)*16 + ((a>>2)^(a&3))): L1 reads CF, writes 2-way-free.

#define NT 256

// ---- ws layout (floats): R4/R12-proven prep ----
#define WS_WCAT 0        // [72 g][256 j][4 c]
#define WS_L1P  73728    // [64 g][128 j][4 c]
#define WS_SW1  106496   // [64 g][256 j][4 c]
#define WS_TOT  172032

// ---- LDS layout (f4 offsets) ----
#define F4_YCT  0        // [4 rows][64] XOR-swizzled y-current
#define F4_HS   256      // [4 rows][64] linear h (RNN/heads source)
#define F4_MID  512      // f32 [4 rows][64] (64 f4)
#define F4_PRR  576      // RNN partials 16 slabs x 65 (alias PH1 32x33)
#define F4_PH1  576
#define F4_PH2  1632     // 16 slabs x 65
#define F4_XS   2672     // [4 rows][8]
#define F4_L1O  2704     // [4][32]
#define F4_SG   2832     // [4][64]
#define F4_W2   3088     // ode_w2: [4 C][13 g][64 ln] (3328)
#define F4_END  6416
#define SM_BC   (F4_END*4)        // 256
#define SM_L1B  (SM_BC+256)       // 128
#define SM_SB1  (SM_L1B+128)      // 256
#define SM_MUW  (SM_SB1+256)      // 128
#define SM_SW2  (SM_MUW+128)      // 256
#define SM_SCL  (SM_SW2+256)      // 4
#define SM_TOTF (SM_SCL+4)
#define SMEM_BYTES (SM_TOTF*4)

__device__ __forceinline__ float fma4(float a, float4 y, float4 w) {
  a = fmaf(y.x, w.x, a); a = fmaf(y.y, w.y, a);
  a = fmaf(y.z, w.z, a); a = fmaf(y.w, w.w, a);
  return a;
}
__device__ __forceinline__ float4 add4(float4 a, float4 b) {
  return make_float4(a.x+b.x, a.y+b.y, a.z+b.z, a.w+b.w);
}
__device__ __forceinline__ float4 axpy4(float a, float4 xv, float4 yv) {
  return make_float4(fmaf(a,xv.x,yv.x), fmaf(a,xv.y,yv.y),
                     fmaf(a,xv.z,yv.z), fmaf(a,xv.w,yv.w));
}
__device__ __forceinline__ float4 muls4(float4 v, float s) {
  return make_float4(v.x*s, v.y*s, v.z*s, v.w*s);
}
__device__ __forceinline__ float tfast(float x) {
  float ax = fabsf(x);
  float e  = __expf(-2.f * ax);
  float t  = (1.f - e) * __builtin_amdgcn_rcpf(1.f + e);
  return copysignf(t, x);
}
__device__ __forceinline__ float4 tfast4(float4 v) {
  return make_float4(tfast(v.x), tfast(v.y), tfast(v.z), tfast(v.w));
}
// DPP butterfly adds (HW-verified R8): after red16 every lane of each
// aligned 16-lane group holds the group sum. Pure VALU.
template <int CTRL>
__device__ __forceinline__ float dpp_add(float v) {
  int s = __builtin_amdgcn_update_dpp(0, __float_as_int(v), CTRL, 0xF, 0xF, true);
  return v + __int_as_float(s);
}
__device__ __forceinline__ float red16(float v) {
  return dpp_add<0xB1>(dpp_add<0x4E>(dpp_add<0x141>(dpp_add<0x140>(v))));
}
// yct swizzle: orig f4 idx a (h comps 4a..4a+3) stored at phys(a).
__device__ __forceinline__ int ycphys(int a) {
  return ((a & 3) << 4) + ((a >> 2) ^ (a & 3));
}

__global__ void prep_w(const float* __restrict__ Wih, const float* __restrict__ Whh,
                       const float* __restrict__ l1w, const float* __restrict__ sw1,
                       float* __restrict__ ws) {
  int i = blockIdx.x * 256 + threadIdx.x;
  if (i < 73728) {                       // Wcat4
    int g = i >> 10, rem = i & 1023, j = rem >> 2, c = rem & 3;
    int k = 4 * g + c;
    ws[i] = (k < 32) ? Wih[j * 32 + k] : Whh[j * 256 + (k - 32)];
  } else if (i < 106496) {               // l1p4
    int t = i - 73728;
    int g = t >> 9, rem = t & 511, j = rem >> 2, c = rem & 3;
    ws[i] = l1w[j * 256 + 4 * g + c];
  } else if (i < WS_TOT) {               // sw1p4
    int t = i - 106496;
    int g = t >> 10, rem = t & 1023, j = rem >> 2, c = rem & 3;
    ws[i] = sw1[j * 256 + 4 * g + c];
  }
}

__global__ __attribute__((amdgpu_flat_work_group_size(NT, NT)))
__attribute__((amdgpu_waves_per_eu(1)))
void odernn_main(const float* __restrict__ dt,
                 const float* __restrict__ x,
                 const float* __restrict__ bih,
                 const float* __restrict__ bhh,
                 const float* __restrict__ ow1,
                 const float* __restrict__ ob1g,
                 const float* __restrict__ ow2,
                 const float* __restrict__ ob2g,
                 const float* __restrict__ l1bg,
                 const float* __restrict__ muwg,
                 const float* __restrict__ mubg,
                 const float* __restrict__ sb1g,
                 const float* __restrict__ sw2g,
                 const float* __restrict__ sb2g,
                 const float* __restrict__ ws,
                 float* __restrict__ out) {
  extern __shared__ __align__(16) float sm[];
  float4* f4 = (float4*)sm;
  float* midS = sm + F4_MID * 4;
  const int tid = threadIdx.x;
  const int wv = tid >> 6, ln = tid & 63;
  const int b0 = blockIdx.x * 4;

  const float4* wcat4 = (const float4*)(ws + WS_WCAT);
  const float4* l1w4  = (const float4*)(ws + WS_L1P);
  const float4* sw14  = (const float4*)(ws + WS_SW1);
  const float4* xg4   = (const float4*)x;

  // ---- persistent per-lane state ----
  const int qA = ln >> 4, kcA = ln & 15;         // L1 lane shape
  float4 w1r[13][4];                             // 208 VGPR
  float  ob1r[13];
#pragma unroll
  for (int jj = 0; jj < 13; ++jj) {
    int j = qA * 13 + jj;
    ob1r[jj] = (j < 50) ? ob1g[j] : 0.f;
#pragma unroll
    for (int f = 0; f < 4; ++f)
      w1r[jj][f] = (j < 50)
          ? *(const float4*)&ow1[j * 256 + kcA * 16 + 4 * f]
          : make_float4(0.f, 0.f, 0.f, 0.f);
  }
  float4 ob2r = *(const float4*)&ob2g[4 * ln];

  // ---- prologue staging ----
  for (int i = tid; i < 3328; i += NT) {         // w2S: [C][g][ln]
    int cg = i >> 6, lq = i & 63;
    int C = cg / 13, g = cg - C * 13;
    int col = 4 * lq + C;
    float t0 = (4*g+0 < 50) ? ow2[col*50 + 4*g+0] : 0.f;
    float t1 = (4*g+1 < 50) ? ow2[col*50 + 4*g+1] : 0.f;
    float t2 = (4*g+2 < 50) ? ow2[col*50 + 4*g+2] : 0.f;
    float t3 = (4*g+3 < 50) ? ow2[col*50 + 4*g+3] : 0.f;
    f4[F4_W2 + i] = make_float4(t0, t1, t2, t3);
  }
  sm[SM_BC + tid] = bih[tid] + bhh[tid];
  sm[SM_SB1 + tid] = sb1g[tid];
  sm[SM_SW2 + tid] = sw2g[tid];
  if (tid < 128) { sm[SM_L1B + tid] = l1bg[tid]; sm[SM_MUW + tid] = muwg[tid]; }
  f4[F4_HS + tid] = make_float4(0.f, 0.f, 0.f, 0.f);
  if (tid < 32) {
    int r = tid >> 3, g = tid & 7;
    f4[F4_XS + tid] = xg4[((size_t)(b0 + r) * 100) * 8 + g];
  } else if (tid < 36) {
    int r = tid - 32;
    const float* dp = dt + ((size_t)(b0 + r) * 100) * 2;
    sm[SM_SCL + r] = (dp[1] - dp[0]) * (1.f / 24.f);
  }
  __syncthreads();

  const float mubv = mubg[0], sb2v = sb2g[0];
  const float4* bc4  = (const float4*)(sm + SM_BC);
  const float4* l1b4 = (const float4*)(sm + SM_L1B);
  const float4* sb14 = (const float4*)(sm + SM_SB1);
  const float4* muw4 = (const float4*)(sm + SM_MUW);
  const float4* sw24 = (const float4*)(sm + SM_SW2);
  const float4* mid4 = (const float4*)midS;      // [4 rows][16]

  const int physW = ycphys(ln);                  // L2/RNN yct write slot
  const int rowb = wv * 64;

  for (int t = 0; t < 100; ++t) {
    // ===== RNN partials (cooperative, 256 thr, 4 rows) — R12 verbatim
    {
      const int jq = tid & 63, kc = tid >> 6;
      float4 a0 = make_float4(0,0,0,0), a1 = a0, a2 = a0, a3 = a0;
#pragma unroll 2
      for (int gg = 0; gg < 18; ++gg) {
        int g = kc * 18 + gg;
        float4 w0 = wcat4[g * 256 + 4 * jq + 0];
        float4 w1 = wcat4[g * 256 + 4 * jq + 1];
        float4 w2 = wcat4[g * 256 + 4 * jq + 2];
        float4 w3 = wcat4[g * 256 + 4 * jq + 3];
        float4 y0 = (g < 8) ? f4[F4_XS + g]      : f4[F4_HS + (g - 8)];
        float4 y1 = (g < 8) ? f4[F4_XS + 8 + g]  : f4[F4_HS + 64 + (g - 8)];
        float4 y2 = (g < 8) ? f4[F4_XS + 16 + g] : f4[F4_HS + 128 + (g - 8)];
        float4 y3 = (g < 8) ? f4[F4_XS + 24 + g] : f4[F4_HS + 192 + (g - 8)];
        a0.x = fma4(a0.x, y0, w0); a0.y = fma4(a0.y, y0, w1);
        a0.z = fma4(a0.z, y0, w2); a0.w = fma4(a0.w, y0, w3);
        a1.x = fma4(a1.x, y1, w0); a1.y = fma4(a1.y, y1, w1);
        a1.z = fma4(a1.z, y1, w2); a1.w = fma4(a1.w, y1, w3);
        a2.x = fma4(a2.x, y2, w0); a2.y = fma4(a2.y, y2, w1);
        a2.z = fma4(a2.z, y2, w2); a2.w = fma4(a2.w, y2, w3);
        a3.x = fma4(a3.x, y3, w0); a3.y = fma4(a3.y, y3, w1);
        a3.z = fma4(a3.z, y3, w2); a3.w = fma4(a3.w, y3, w3);
      }
      f4[F4_PRR + (kc * 4 + 0) * 65 + jq] = a0;
      f4[F4_PRR + (kc * 4 + 1) * 65 + jq] = a1;
      f4[F4_PRR + (kc * 4 + 2) * 65 + jq] = a2;
      f4[F4_PRR + (kc * 4 + 3) * 65 + jq] = a3;
    }
    __syncthreads();                                   // bar A
    // ===== RNN reduce (per-wave: row = wv) -> h' in reg + yct
    float4 h;
    {
      float4 v = bc4[ln];
#pragma unroll
      for (int kc = 0; kc < 4; ++kc)
        v = add4(v, f4[F4_PRR + (kc * 4 + wv) * 65 + ln]);
      h = add4(f4[F4_HS + rowb + ln], tfast4(v));
      f4[F4_YCT + rowb + physW] = h;
    }
    // ===== wave-fused eval: 16 RK4 stages, NO barriers (intra-wave lgkm)
    float4 ac = make_float4(0.f, 0.f, 0.f, 0.f);
    const float sc = sm[SM_SCL + wv];
#pragma unroll 1
    for (int e = 0; e < 16; ++e) {
      // --- L1: yc swizzled reads (CF), 52 fma4, red16, mid write
      float4 y0 = f4[F4_YCT + rowb + 0 * 16 + (kcA ^ 0)];
      float4 y1 = f4[F4_YCT + rowb + 1 * 16 + (kcA ^ 1)];
      float4 y2 = f4[F4_YCT + rowb + 2 * 16 + (kcA ^ 2)];
      float4 y3 = f4[F4_YCT + rowb + 3 * 16 + (kcA ^ 3)];
      float p[13];
#pragma unroll
      for (int jj = 0; jj < 13; ++jj) {
        float s = 0.f;
        s = fma4(s, y0, w1r[jj][0]); s = fma4(s, y1, w1r[jj][1]);
        s = fma4(s, y2, w1r[jj][2]); s = fma4(s, y3, w1r[jj][3]);
        p[jj] = s;
      }
#pragma unroll
      for (int jj = 0; jj < 13; ++jj) p[jj] = red16(p[jj]);
      if (kcA == 0) {
#pragma unroll
        for (int jj = 0; jj < 13; ++jj)
          midS[wv * 64 + qA * 13 + jj] = tfast(p[jj] + ob1r[jj]);
      }
      // --- L2: mid broadcasts + w2S lane reads, 52 fma4, RK4 in regs
      float bx = 0.f, by = 0.f, bz = 0.f, bw = 0.f;
#pragma unroll
      for (int g = 0; g < 13; ++g) {
        float4 m = mid4[wv * 16 + g];
        bx = fma4(bx, m, f4[F4_W2 + (0 * 13 + g) * 64 + ln]);
        by = fma4(by, m, f4[F4_W2 + (1 * 13 + g) * 64 + ln]);
        bz = fma4(bz, m, f4[F4_W2 + (2 * 13 + g) * 64 + ln]);
        bw = fma4(bw, m, f4[F4_W2 + (3 * 13 + g) * 64 + ln]);
      }
      float4 kv = muls4(add4(make_float4(bx, by, bz, bw), ob2r), sc);
      const int s = e & 3;
      float4 ycw;
      if (s == 0)      { ac = kv;                 ycw = axpy4(0.125f, kv, h); }
      else if (s == 1) { ac = axpy4(2.f, kv, ac); ycw = axpy4(0.125f, kv, h); }
      else if (s == 2) { ac = axpy4(2.f, kv, ac); ycw = axpy4(0.25f,  kv, h); }
      else             { h = axpy4(0.25f / 6.f, add4(ac, kv), h); ycw = h; }
      f4[F4_YCT + rowb + physW] = ycw;
    }
    f4[F4_HS + rowb + ln] = h;                         // final h for heads/RNN
    __syncthreads();                                   // bar B

    // ===== heads partials (R12 verbatim, source F4_HS) + stage next x/scl
    {
      const int cq = tid & 31, kc = tid >> 5;
      float4 c0 = make_float4(0,0,0,0), c1 = c0, c2 = c0, c3 = c0;
#pragma unroll 2
      for (int g = 0; g < 8; ++g) {
        int kg = kc * 8 + g;
        float4 w0 = l1w4[kg * 128 + 4 * cq + 0];
        float4 w1 = l1w4[kg * 128 + 4 * cq + 1];
        float4 w2 = l1w4[kg * 128 + 4 * cq + 2];
        float4 w3 = l1w4[kg * 128 + 4 * cq + 3];
        float4 y0 = f4[F4_HS + kg],       y1 = f4[F4_HS + 64 + kg];
        float4 y2 = f4[F4_HS + 128 + kg], y3 = f4[F4_HS + 192 + kg];
        c0.x = fma4(c0.x, y0, w0); c0.y = fma4(c0.y, y0, w1);
        c0.z = fma4(c0.z, y0, w2); c0.w = fma4(c0.w, y0, w3);
        c1.x = fma4(c1.x, y1, w0); c1.y = fma4(c1.y, y1, w1);
        c1.z = fma4(c1.z, y1, w2); c1.w = fma4(c1.w, y1, w3);
        c2.x = fma4(c2.x, y2, w0); c2.y = fma4(c2.y, y2, w1);
        c2.z = fma4(c2.z, y2, w2); c2.w = fma4(c2.w, y2, w3);
        c3.x = fma4(c3.x, y3, w0); c3.y = fma4(c3.y, y3, w1);
        c3.z = fma4(c3.z, y3, w2); c3.w = fma4(c3.w, y3, w3);
      }
      f4[F4_PH1 + (kc * 4 + 0) * 33 + cq] = c0;
      f4[F4_PH1 + (kc * 4 + 1) * 33 + cq] = c1;
      f4[F4_PH1 + (kc * 4 + 2) * 33 + cq] = c2;
      f4[F4_PH1 + (kc * 4 + 3) * 33 + cq] = c3;
    }
    {
      const int cq = tid & 63, kc = tid >> 6;
      float4 d0 = make_float4(0,0,0,0), d1 = d0, d2 = d0, d3 = d0;
#pragma unroll 2
      for (int g = 0; g < 16; ++g) {
        int kg = kc * 16 + g;
        float4 w0 = sw14[kg * 256 + 4 * cq + 0];
        float4 w1 = sw14[kg * 256 + 4 * cq + 1];
        float4 w2 = sw14[kg * 256 + 4 * cq + 2];
        float4 w3 = sw14[kg * 256 + 4 * cq + 3];
        float4 y0 = f4[F4_HS + kg],       y1 = f4[F4_HS + 64 + kg];
        float4 y2 = f4[F4_HS + 128 + kg], y3 = f4[F4_HS + 192 + kg];
        d0.x = fma4(d0.x, y0, w0); d0.y = fma4(d0.y, y0, w1);
        d0.z = fma4(d0.z, y0, w2); d0.w = fma4(d0.w, y0, w3);
        d1.x = fma4(d1.x, y1, w0); d1.y = fma4(d1.y, y1, w1);
        d1.z = fma4(d1.z, y1, w2); d1.w = fma4(d1.w, y1, w3);
        d2.x = fma4(d2.x, y2, w0); d2.y = fma4(d2.y, y2, w1);
        d2.z = fma4(d2.z, y2, w2); d2.w = fma4(d2.w, y2, w3);
        d3.x = fma4(d3.x, y3, w0); d3.y = fma4(d3.y, y3, w1);
        d3.z = fma4(d3.z, y3, w2); d3.w = fma4(d3.w, y3, w3);
      }
      f4[F4_PH2 + (kc * 4 + 0) * 65 + cq] = d0;
      f4[F4_PH2 + (kc * 4 + 1) * 65 + cq] = d1;
      f4[F4_PH2 + (kc * 4 + 2) * 65 + cq] = d2;
      f4[F4_PH2 + (kc * 4 + 3) * 65 + cq] = d3;
    }
    if (t < 99) {                                      // stage next x / scl
      if (tid < 32) {
        int r = tid >> 3, g = tid & 7;
        f4[F4_XS + tid] = xg4[((size_t)(b0 + r) * 100 + t + 1) * 8 + g];
      } else if (tid < 36) {
        int r = tid - 32;
        const float* dp = dt + ((size_t)(b0 + r) * 100 + t + 1) * 2;
        sm[SM_SCL + r] = (dp[1] - dp[0]) * (1.f / 24.f);
      }
    }
    __syncthreads();                                   // bar C
    // ===== head reduces
    if (tid < 128) {
      int r = tid >> 5, cq = tid & 31;
      float4 v = l1b4[cq];
#pragma unroll
      for (int kc = 0; kc < 8; ++kc)
        v = add4(v, f4[F4_PH1 + (kc * 4 + r) * 33 + cq]);
      f4[F4_L1O + r * 32 + cq] =
          make_float4(fmaxf(v.x, 0.f), fmaxf(v.y, 0.f),
                      fmaxf(v.z, 0.f), fmaxf(v.w, 0.f));
    }
    {
      int r = tid >> 6, cq = tid & 63;
      float4 v = sb14[cq];
#pragma unroll
      for (int kc = 0; kc < 4; ++kc)
        v = add4(v, f4[F4_PH2 + (kc * 4 + r) * 65 + cq]);
      f4[F4_SG + r * 64 + cq] = tfast4(v);
    }
    __syncthreads();                                   // bar D
    // ===== final dots: wave wv -> row wv (mu + sigma)
    {
      float pm = 0.f;
      if (ln < 32) {
        float4 l = f4[F4_L1O + wv * 32 + ln];
        float4 w = muw4[ln];
        pm = l.x * w.x + l.y * w.y + l.z * w.z + l.w * w.w;
      }
#pragma unroll
      for (int off = 32; off > 0; off >>= 1) pm += __shfl_down(pm, off);
      if (ln == 0) out[(size_t)(b0 + wv) * 100 + t] = pm + mubv;
      float4 sv = f4[F4_SG + wv * 64 + ln];
      float4 w2v = sw24[ln];
      float ps = sv.x * w2v.x + sv.y * w2v.y + sv.z * w2v.z + sv.w * w2v.w;
#pragma unroll
      for (int off = 32; off > 0; off >>= 1) ps += __shfl_down(ps, off);
      if (ln == 0) {
        float z = ps + sb2v;
        float sp = fmaxf(z, 0.f) + log1pf(expf(-fabsf(z)));
        out[(size_t)102400 + (size_t)(b0 + wv) * 100 + t] = sp;
      }
    }
    // no bar: next RNNPART writes PRR (disjoint from L1O/SG reads above are
    // done per-wave before it proceeds; cross-wave PH/PRR reuse is fenced by
    // bar D (all HEADSRED reads completed before any wave passed it).
  }
}

extern "C" void kernel_launch(void* const* d_in, const int* in_sizes, int n_in,
                              void* d_out, int out_size, void* d_ws, size_t ws_size,
                              hipStream_t stream) {
  const float* dt  = (const float*)d_in[0];
  const float* x   = (const float*)d_in[1];
  const float* Wih = (const float*)d_in[2];
  const float* bih = (const float*)d_in[3];
  const float* Whh = (const float*)d_in[4];
  const float* bhh = (const float*)d_in[5];
  const float* ow1 = (const float*)d_in[6];
  const float* ob1 = (const float*)d_in[7];
  const float* ow2 = (const float*)d_in[8];
  const float* ob2 = (const float*)d_in[9];
  const float* l1w = (const float*)d_in[10];
  const float* l1b = (const float*)d_in[11];
  const float* muw = (const float*)d_in[12];
  const float* mub = (const float*)d_in[13];
  const float* sw1 = (const float*)d_in[14];
  const float* sb1 = (const float*)d_in[15];
  const float* sw2 = (const float*)d_in[16];
  const float* sb2 = (const float*)d_in[17];
  float* ws  = (float*)d_ws;
  float* out = (float*)d_out;

  hipFuncSetAttribute((const void*)odernn_main,
                      hipFuncAttributeMaxDynamicSharedMemorySize, SMEM_BYTES);

  prep_w<<<WS_TOT / 256, 256, 0, stream>>>(Wih, Whh, l1w, sw1, ws);
  odernn_main<<<256, NT, SMEM_BYTES, stream>>>(dt, x, bih, bhh, ow1, ob1, ow2, ob2,
                                               l1b, muw, mub, sb1, sw2, sb2, ws, out);
}

// Round 14
// 3283.770 us; speedup vs baseline: 1.4465x; 1.4465x over previous
//
#include <hip/hip_runtime.h>
#include <math.h>

// ODE-RNN forward: B=1024, T=100, D=32, H=256, MID=50 (pad 52), RK4x4.
// Round 14: R12 base (3.32ms winner: wave-specialized A/B dual pipeline,
// reg-resident weights, thin phases) + yct XOR-swizzle (kills the 8.2e7
// 4-way conflict on L1's yc reads; swizzle verified correct in R13) +
// waves_per_eu(1) (more arch VGPRs -> less AGPR parking of w1r).
// Final h mirrored to linear F4_HS for RNN/heads (patterns unchanged).

#define NT 256

// ---- ws layout (floats): R4/R12-proven prep ----
#define WS_WCAT 0        // [72 g][256 j][4 c]
#define WS_L1P  73728    // [64 g][128 j][4 c]
#define WS_SW1  106496   // [64 g][256 j][4 c]
#define WS_TOT  172032

// ---- LDS layout (f4 offsets) ----
#define F4_YC   0        // [4 rows][64] SWIZZLED y-current
#define F4_MID  256      // f32 [4 rows][64] (64 f4)
#define F4_PRR  320      // RNN partials 16 slabs x 65 (alias PH1 32x33)
#define F4_PH1  320
#define F4_PH2  1376     // 16 slabs x 65
#define F4_XS   2416     // [4 rows][8]
#define F4_L1O  2448     // [4][32]
#define F4_SG   2576     // [4][64]
#define F4_W1   2832     // ode_w1 staged: [52 j][4 f][16 kc] (3328)
#define F4_W2   6160     // ode_w2 staged: [4 C][13 g][64 ln] (3328)
#define F4_HS   9488     // [4 rows][64] LINEAR final h (RNN/heads source)
#define F4_END  9744
#define SM_BC   (F4_END*4)        // 256
#define SM_OB2  (SM_BC+256)       // 256
#define SM_L1B  (SM_OB2+256)      // 128
#define SM_SB1  (SM_L1B+128)      // 256
#define SM_MUW  (SM_SB1+256)      // 128
#define SM_SW2  (SM_MUW+128)      // 256
#define SM_SCL  (SM_SW2+256)      // 4
#define SM_TOTF (SM_SCL+4)
#define SMEM_BYTES (SM_TOTF*4)

__device__ __forceinline__ float fma4(float a, float4 y, float4 w) {
  a = fmaf(y.x, w.x, a); a = fmaf(y.y, w.y, a);
  a = fmaf(y.z, w.z, a); a = fmaf(y.w, w.w, a);
  return a;
}
__device__ __forceinline__ float4 add4(float4 a, float4 b) {
  return make_float4(a.x+b.x, a.y+b.y, a.z+b.z, a.w+b.w);
}
__device__ __forceinline__ float4 axpy4(float a, float4 xv, float4 yv) {
  return make_float4(fmaf(a,xv.x,yv.x), fmaf(a,xv.y,yv.y),
                     fmaf(a,xv.z,yv.z), fmaf(a,xv.w,yv.w));
}
__device__ __forceinline__ float4 muls4(float4 v, float s) {
  return make_float4(v.x*s, v.y*s, v.z*s, v.w*s);
}
__device__ __forceinline__ float tfast(float x) {
  float ax = fabsf(x);
  float e  = __expf(-2.f * ax);
  float t  = (1.f - e) * __builtin_amdgcn_rcpf(1.f + e);
  return copysignf(t, x);
}
__device__ __forceinline__ float4 tfast4(float4 v) {
  return make_float4(tfast(v.x), tfast(v.y), tfast(v.z), tfast(v.w));
}
// DPP butterfly adds (HW-verified R8). Pure VALU.
template <int CTRL>
__device__ __forceinline__ float dpp_add(float v) {
  int s = __builtin_amdgcn_update_dpp(0, __float_as_int(v), CTRL, 0xF, 0xF, true);
  return v + __int_as_float(s);
}
__device__ __forceinline__ float red16(float v) {
  return dpp_add<0xB1>(dpp_add<0x4E>(dpp_add<0x141>(dpp_add<0x140>(v))));
}
// yc swizzle (verified R13): logical f4 idx a stored at phys(a).
// L1 reads (a = kcA*4+j) -> j*16 + (kcA^j): conflict-free.
// Linear-lane writes (a = ln): 2 lanes/bank-quad = free (m136).
__device__ __forceinline__ int ycphys(int a) {
  return ((a & 3) << 4) + ((a >> 2) ^ (a & 3));
}

__global__ void prep_w(const float* __restrict__ Wih, const float* __restrict__ Whh,
                       const float* __restrict__ l1w, const float* __restrict__ sw1,
                       float* __restrict__ ws) {
  int i = blockIdx.x * 256 + threadIdx.x;
  if (i < 73728) {                       // Wcat4
    int g = i >> 10, rem = i & 1023, j = rem >> 2, c = rem & 3;
    int k = 4 * g + c;
    ws[i] = (k < 32) ? Wih[j * 32 + k] : Whh[j * 256 + (k - 32)];
  } else if (i < 106496) {               // l1p4
    int t = i - 73728;
    int g = t >> 9, rem = t & 511, j = rem >> 2, c = rem & 3;
    ws[i] = l1w[j * 256 + 4 * g + c];
  } else if (i < WS_TOT) {               // sw1p4
    int t = i - 106496;
    int g = t >> 10, rem = t & 1023, j = rem >> 2, c = rem & 3;
    ws[i] = sw1[j * 256 + 4 * g + c];
  }
}

__global__ __attribute__((amdgpu_flat_work_group_size(NT, NT)))
__attribute__((amdgpu_waves_per_eu(1)))
void odernn_main(const float* __restrict__ dt,
                 const float* __restrict__ x,
                 const float* __restrict__ bih,
                 const float* __restrict__ bhh,
                 const float* __restrict__ ow1,
                 const float* __restrict__ ob1g,
                 const float* __restrict__ ow2,
                 const float* __restrict__ ob2g,
                 const float* __restrict__ l1bg,
                 const float* __restrict__ muwg,
                 const float* __restrict__ mubg,
                 const float* __restrict__ sb1g,
                 const float* __restrict__ sw2g,
                 const float* __restrict__ sb2g,
                 const float* __restrict__ ws,
                 float* __restrict__ out) {
  extern __shared__ __align__(16) float sm[];
  float4* f4 = (float4*)sm;
  float* midS = sm + F4_MID * 4;                 // f32 [4][64]
  const int tid = threadIdx.x;
  const int wv = tid >> 6, ln = tid & 63;
  const int b0 = blockIdx.x * 4;
  const bool isA = (wv & 1) == 0;
  const int ra = (wv >> 1) * 2, rb = ra + 1;     // pipeline rows

  const float4* wcat4 = (const float4*)(ws + WS_WCAT);
  const float4* l1w4  = (const float4*)(ws + WS_L1P);
  const float4* sw14  = (const float4*)(ws + WS_SW1);
  const float4* xg4   = (const float4*)x;

  // ---------- prologue: stage weights to LDS, biases, x, scl, h=0 ----------
  for (int i = tid; i < 3328; i += NT) {         // w1: [j][f][kc]
    int j = i >> 6, rem = i & 63, f = rem >> 4, kq = rem & 15;
    float4 v = make_float4(0.f, 0.f, 0.f, 0.f);
    if (j < 50) v = *(const float4*)&ow1[j * 256 + kq * 16 + 4 * f];
    f4[F4_W1 + (j * 4 + f) * 16 + kq] = v;
  }
  for (int i = tid; i < 3328; i += NT) {         // w2: [C][g][ln]
    int cg = i >> 6, lq = i & 63;
    int C = cg / 13, g = cg - C * 13;
    int col = 4 * lq + C;
    float t0 = (4*g+0 < 50) ? ow2[col*50 + 4*g+0] : 0.f;
    float t1 = (4*g+1 < 50) ? ow2[col*50 + 4*g+1] : 0.f;
    float t2 = (4*g+2 < 50) ? ow2[col*50 + 4*g+2] : 0.f;
    float t3 = (4*g+3 < 50) ? ow2[col*50 + 4*g+3] : 0.f;
    f4[F4_W2 + i] = make_float4(t0, t1, t2, t3);
  }
  sm[SM_BC + tid]  = bih[tid] + bhh[tid];
  sm[SM_OB2 + tid] = ob2g[tid];
  sm[SM_SB1 + tid] = sb1g[tid];
  sm[SM_SW2 + tid] = sw2g[tid];
  if (tid < 128) { sm[SM_L1B + tid] = l1bg[tid]; sm[SM_MUW + tid] = muwg[tid]; }
  f4[F4_HS + tid] = make_float4(0.f, 0.f, 0.f, 0.f);   // h0 = 0 (4x64)
  if (tid < 32) {
    int r = tid >> 3, g = tid & 7;
    f4[F4_XS + tid] = xg4[((size_t)(b0 + r) * 100) * 8 + g];
  } else if (tid < 36) {
    int r = tid - 32;
    const float* dp = dt + ((size_t)(b0 + r) * 100) * 2;
    sm[SM_SCL + r] = (dp[1] - dp[0]) * (1.f / 24.f);
  }
  __syncthreads();

  const float mubv = mubg[0], sb2v = sb2g[0];
  const float4* bc4  = (const float4*)(sm + SM_BC);
  const float4* l1b4 = (const float4*)(sm + SM_L1B);
  const float4* sb14 = (const float4*)(sm + SM_SB1);
  const float4* muw4 = (const float4*)(sm + SM_MUW);
  const float4* sw24 = (const float4*)(sm + SM_SW2);

  // ---------- shared phase lambdas ----------
  auto RNNPART = [&]() {
    const int jq = tid & 63, kc = tid >> 6;      // kc 0..3, 18 g-chunks each
    float4 a0 = make_float4(0,0,0,0), a1 = a0, a2 = a0, a3 = a0;
#pragma unroll 2
    for (int gg = 0; gg < 18; ++gg) {
      int g = kc * 18 + gg;
      float4 w0 = wcat4[g * 256 + 4 * jq + 0];
      float4 w1 = wcat4[g * 256 + 4 * jq + 1];
      float4 w2 = wcat4[g * 256 + 4 * jq + 2];
      float4 w3 = wcat4[g * 256 + 4 * jq + 3];
      float4 y0 = (g < 8) ? f4[F4_XS + g]      : f4[F4_HS + (g - 8)];
      float4 y1 = (g < 8) ? f4[F4_XS + 8 + g]  : f4[F4_HS + 64 + (g - 8)];
      float4 y2 = (g < 8) ? f4[F4_XS + 16 + g] : f4[F4_HS + 128 + (g - 8)];
      float4 y3 = (g < 8) ? f4[F4_XS + 24 + g] : f4[F4_HS + 192 + (g - 8)];
      a0.x = fma4(a0.x, y0, w0); a0.y = fma4(a0.y, y0, w1);
      a0.z = fma4(a0.z, y0, w2); a0.w = fma4(a0.w, y0, w3);
      a1.x = fma4(a1.x, y1, w0); a1.y = fma4(a1.y, y1, w1);
      a1.z = fma4(a1.z, y1, w2); a1.w = fma4(a1.w, y1, w3);
      a2.x = fma4(a2.x, y2, w0); a2.y = fma4(a2.y, y2, w1);
      a2.z = fma4(a2.z, y2, w2); a2.w = fma4(a2.w, y2, w3);
      a3.x = fma4(a3.x, y3, w0); a3.y = fma4(a3.y, y3, w1);
      a3.z = fma4(a3.z, y3, w2); a3.w = fma4(a3.w, y3, w3);
    }
    f4[F4_PRR + (kc * 4 + 0) * 65 + jq] = a0;
    f4[F4_PRR + (kc * 4 + 1) * 65 + jq] = a1;
    f4[F4_PRR + (kc * 4 + 2) * 65 + jq] = a2;
    f4[F4_PRR + (kc * 4 + 3) * 65 + jq] = a3;
  };
  auto RNNRED = [&]() {
    const int r = tid >> 6, jq = tid & 63;
    float4 v = bc4[jq];
#pragma unroll
    for (int kc = 0; kc < 4; ++kc)
      v = add4(v, f4[F4_PRR + (kc * 4 + r) * 65 + jq]);
    float4 hold = f4[F4_HS + r * 64 + jq];
    f4[F4_YC + r * 64 + ycphys(jq)] = add4(hold, tfast4(v));   // swizzled
  };
  auto HEADSPART = [&]() {
    {  // mu-l1 partials: (cq 32, kc 8)
      const int cq = tid & 31, kc = tid >> 5;
      float4 c0 = make_float4(0,0,0,0), c1 = c0, c2 = c0, c3 = c0;
#pragma unroll 2
      for (int g = 0; g < 8; ++g) {
        int kg = kc * 8 + g;
        float4 w0 = l1w4[kg * 128 + 4 * cq + 0];
        float4 w1 = l1w4[kg * 128 + 4 * cq + 1];
        float4 w2 = l1w4[kg * 128 + 4 * cq + 2];
        float4 w3 = l1w4[kg * 128 + 4 * cq + 3];
        float4 y0 = f4[F4_HS + kg],       y1 = f4[F4_HS + 64 + kg];
        float4 y2 = f4[F4_HS + 128 + kg], y3 = f4[F4_HS + 192 + kg];
        c0.x = fma4(c0.x, y0, w0); c0.y = fma4(c0.y, y0, w1);
        c0.z = fma4(c0.z, y0, w2); c0.w = fma4(c0.w, y0, w3);
        c1.x = fma4(c1.x, y1, w0); c1.y = fma4(c1.y, y1, w1);
        c1.z = fma4(c1.z, y1, w2); c1.w = fma4(c1.w, y1, w3);
        c2.x = fma4(c2.x, y2, w0); c2.y = fma4(c2.y, y2, w1);
        c2.z = fma4(c2.z, y2, w2); c2.w = fma4(c2.w, y2, w3);
        c3.x = fma4(c3.x, y3, w0); c3.y = fma4(c3.y, y3, w1);
        c3.z = fma4(c3.z, y3, w2); c3.w = fma4(c3.w, y3, w3);
      }
      f4[F4_PH1 + (kc * 4 + 0) * 33 + cq] = c0;
      f4[F4_PH1 + (kc * 4 + 1) * 33 + cq] = c1;
      f4[F4_PH1 + (kc * 4 + 2) * 33 + cq] = c2;
      f4[F4_PH1 + (kc * 4 + 3) * 33 + cq] = c3;
    }
    {  // sig-l1 partials: (cq 64, kc 4)
      const int cq = tid & 63, kc = tid >> 6;
      float4 d0 = make_float4(0,0,0,0), d1 = d0, d2 = d0, d3 = d0;
#pragma unroll 2
      for (int g = 0; g < 16; ++g) {
        int kg = kc * 16 + g;
        float4 w0 = sw14[kg * 256 + 4 * cq + 0];
        float4 w1 = sw14[kg * 256 + 4 * cq + 1];
        float4 w2 = sw14[kg * 256 + 4 * cq + 2];
        float4 w3 = sw14[kg * 256 + 4 * cq + 3];
        float4 y0 = f4[F4_HS + kg],       y1 = f4[F4_HS + 64 + kg];
        float4 y2 = f4[F4_HS + 128 + kg], y3 = f4[F4_HS + 192 + kg];
        d0.x = fma4(d0.x, y0, w0); d0.y = fma4(d0.y, y0, w1);
        d0.z = fma4(d0.z, y0, w2); d0.w = fma4(d0.w, y0, w3);
        d1.x = fma4(d1.x, y1, w0); d1.y = fma4(d1.y, y1, w1);
        d1.z = fma4(d1.z, y1, w2); d1.w = fma4(d1.w, y1, w3);
        d2.x = fma4(d2.x, y2, w0); d2.y = fma4(d2.y, y2, w1);
        d2.z = fma4(d2.z, y2, w2); d2.w = fma4(d2.w, y2, w3);
        d3.x = fma4(d3.x, y3, w0); d3.y = fma4(d3.y, y3, w1);
        d3.z = fma4(d3.z, y3, w2); d3.w = fma4(d3.w, y3, w3);
      }
      f4[F4_PH2 + (kc * 4 + 0) * 65 + cq] = d0;
      f4[F4_PH2 + (kc * 4 + 1) * 65 + cq] = d1;
      f4[F4_PH2 + (kc * 4 + 2) * 65 + cq] = d2;
      f4[F4_PH2 + (kc * 4 + 3) * 65 + cq] = d3;
    }
  };
  auto HEADSRED = [&]() {
    if (tid < 128) {
      int r = tid >> 5, cq = tid & 31;
      float4 v = l1b4[cq];
#pragma unroll
      for (int kc = 0; kc < 8; ++kc)
        v = add4(v, f4[F4_PH1 + (kc * 4 + r) * 33 + cq]);
      f4[F4_L1O + r * 32 + cq] =
          make_float4(fmaxf(v.x, 0.f), fmaxf(v.y, 0.f),
                      fmaxf(v.z, 0.f), fmaxf(v.w, 0.f));
    }
    {
      int r = tid >> 6, cq = tid & 63;
      float4 v = sb14[cq];
#pragma unroll
      for (int kc = 0; kc < 4; ++kc)
        v = add4(v, f4[F4_PH2 + (kc * 4 + r) * 65 + cq]);
      f4[F4_SG + r * 64 + cq] = tfast4(v);
    }
  };
  auto DOTS = [&](int t) {
    float pm = 0.f;
    if (ln < 32) {
      float4 l = f4[F4_L1O + wv * 32 + ln];
      float4 w = muw4[ln];
      pm = l.x * w.x + l.y * w.y + l.z * w.z + l.w * w.w;
    }
#pragma unroll
    for (int off = 32; off > 0; off >>= 1) pm += __shfl_down(pm, off);
    if (ln == 0) out[(size_t)(b0 + wv) * 100 + t] = pm + mubv;
    float4 sv = f4[F4_SG + wv * 64 + ln];
    float4 w2v = sw24[ln];
    float ps = sv.x * w2v.x + sv.y * w2v.y + sv.z * w2v.z + sv.w * w2v.w;
#pragma unroll
    for (int off = 32; off > 0; off >>= 1) ps += __shfl_down(ps, off);
    if (ln == 0) {
      float z = ps + sb2v;
      float sp = fmaxf(z, 0.f) + log1pf(expf(-fabsf(z)));
      out[(size_t)102400 + (size_t)(b0 + wv) * 100 + t] = sp;
    }
  };

  if (isA) {
    // =================== A side: ODE layer-1 for rows ra, rb ===============
    const int qA = ln >> 4, kcA = ln & 15;
    float4 w1r[13][4];
    float ob1A = 0.f;
    {
      int jb = qA * 13 + kcA;
      if (kcA < 13 && jb < 50) ob1A = ob1g[jb];
    }
    auto L1 = [&](int row) {
      // swizzled CF reads: logical a = kcA*4+j -> phys = j*16 + (kcA^j)
      float4 y0 = f4[F4_YC + row * 64 + 0 * 16 + (kcA ^ 0)];
      float4 y1 = f4[F4_YC + row * 64 + 1 * 16 + (kcA ^ 1)];
      float4 y2 = f4[F4_YC + row * 64 + 2 * 16 + (kcA ^ 2)];
      float4 y3 = f4[F4_YC + row * 64 + 3 * 16 + (kcA ^ 3)];
      float p[13];
#pragma unroll
      for (int jj = 0; jj < 13; ++jj) {
        float s = 0.f;
        s = fma4(s, y0, w1r[jj][0]); s = fma4(s, y1, w1r[jj][1]);
        s = fma4(s, y2, w1r[jj][2]); s = fma4(s, y3, w1r[jj][3]);
        p[jj] = s;
      }
#pragma unroll
      for (int jj = 0; jj < 13; ++jj) p[jj] = red16(p[jj]);
      if (kcA < 13) {
        float v = p[0];
#pragma unroll
        for (int jj = 1; jj < 13; ++jj) v = (kcA == jj) ? p[jj] : v;
        midS[row * 64 + qA * 13 + kcA] = tfast(v + ob1A);
      }
    };

    for (int t = 0; t < 100; ++t) {
      RNNPART();  __syncthreads();
      RNNRED();   __syncthreads();
      // reload w1 from LDS (dead during RNN/heads -> no spill)
#pragma unroll
      for (int jj = 0; jj < 13; ++jj)
#pragma unroll
        for (int f = 0; f < 4; ++f)
          w1r[jj][f] = f4[F4_W1 + ((qA * 13 + jj) * 4 + f) * 16 + kcA];
#pragma unroll 1
      for (int ph = 0; ph <= 32; ++ph) {
        if (ph < 32) {
          L1(ra + (ph & 1));
        } else if (t < 99 && wv == 0) {          // stage next x / scl
          if (ln < 32) {
            int r = ln >> 3, g = ln & 7;
            f4[F4_XS + ln] = xg4[((size_t)(b0 + r) * 100 + t + 1) * 8 + g];
          } else if (ln < 36) {
            int r = ln - 32;
            const float* dp = dt + ((size_t)(b0 + r) * 100 + t + 1) * 2;
            sm[SM_SCL + r] = (dp[1] - dp[0]) * (1.f / 24.f);
          }
        }
        __syncthreads();
      }
      HEADSPART(); __syncthreads();
      HEADSRED();  __syncthreads();
      DOTS(t);     __syncthreads();
    }
  } else {
    // ============ B side: ODE layer-2 + RK4 state for rows ra, rb ==========
    float4 w2c0[13], w2c1[13], w2c2[13], w2c3[13];
    float4 hA, hB, acA, acB;
    float sclA = 0.f, sclB = 0.f;
    const int physW = ycphys(ln);
    auto L2 = [&](int row, int e, float4& h, float4& ac, float sc) {
      const float4* mr = (const float4*)(midS + row * 64);
      float bx = 0.f, by = 0.f, bz = 0.f, bw = 0.f;
#define L2STEP(mv, g) bx = fma4(bx, mv, w2c0[g]); by = fma4(by, mv, w2c1[g]); \
                      bz = fma4(bz, mv, w2c2[g]); bw = fma4(bw, mv, w2c3[g]);
      {
        float4 a0 = mr[0], a1 = mr[1], a2 = mr[2], a3 = mr[3], a4 = mr[4];
        L2STEP(a0, 0) L2STEP(a1, 1) L2STEP(a2, 2) L2STEP(a3, 3) L2STEP(a4, 4)
      }
      {
        float4 a0 = mr[5], a1 = mr[6], a2 = mr[7], a3 = mr[8];
        L2STEP(a0, 5) L2STEP(a1, 6) L2STEP(a2, 7) L2STEP(a3, 8)
      }
      {
        float4 a0 = mr[9], a1 = mr[10], a2 = mr[11], a3 = mr[12];
        L2STEP(a0, 9) L2STEP(a1, 10) L2STEP(a2, 11) L2STEP(a3, 12)
      }
#undef L2STEP
      float4 ob2v = ((const float4*)(sm + SM_OB2))[ln];
      float4 kv = muls4(add4(make_float4(bx, by, bz, bw), ob2v), sc);
      const int s = e & 3;
      float4 ycw;
      if (s == 0)      { ac = kv;                 ycw = axpy4(0.125f, kv, h); }
      else if (s == 1) { ac = axpy4(2.f, kv, ac); ycw = axpy4(0.125f, kv, h); }
      else if (s == 2) { ac = axpy4(2.f, kv, ac); ycw = axpy4(0.25f,  kv, h); }
      else             { h = axpy4(0.25f / 6.f, add4(ac, kv), h); ycw = h; }
      f4[F4_YC + row * 64 + physW] = ycw;          // swizzled (2-way free)
      if (e == 15)
        f4[F4_HS + row * 64 + ln] = h;             // linear final h
    };

    for (int t = 0; t < 100; ++t) {
      RNNPART();  __syncthreads();
      RNNRED();   __syncthreads();
      // reload w2 from LDS
#pragma unroll
      for (int g = 0; g < 13; ++g) {
        w2c0[g] = f4[F4_W2 + (0 * 13 + g) * 64 + ln];
        w2c1[g] = f4[F4_W2 + (1 * 13 + g) * 64 + ln];
        w2c2[g] = f4[F4_W2 + (2 * 13 + g) * 64 + ln];
        w2c3[g] = f4[F4_W2 + (3 * 13 + g) * 64 + ln];
      }
#pragma unroll 1
      for (int ph = 0; ph <= 32; ++ph) {
        if (ph == 0) {
          hA = f4[F4_YC + ra * 64 + physW];        // swizzled read (2-way)
          hB = f4[F4_YC + rb * 64 + physW];
          acA = make_float4(0.f, 0.f, 0.f, 0.f); acB = acA;
          sclA = sm[SM_SCL + ra]; sclB = sm[SM_SCL + rb];
        } else if (ph & 1) {
          L2(ra, (ph - 1) >> 1, hA, acA, sclA);
        } else {
          L2(rb, (ph - 2) >> 1, hB, acB, sclB);
        }
        __syncthreads();
      }
      HEADSPART(); __syncthreads();
      HEADSRED();  __syncthreads();
      DOTS(t);     __syncthreads();
    }
  }
}

extern "C" void kernel_launch(void* const* d_in, const int* in_sizes, int n_in,
                              void* d_out, int out_size, void* d_ws, size_t ws_size,
                              hipStream_t stream) {
  const float* dt  = (const float*)d_in[0];
  const float* x   = (const float*)d_in[1];
  const float* Wih = (const float*)d_in[2];
  const float* bih = (const float*)d_in[3];
  const float* Whh = (const float*)d_in[4];
  const float* bhh = (const float*)d_in[5];
  const float* ow1 = (const float*)d_in[6];
  const float* ob1 = (const float*)d_in[7];
  const float* ow2 = (const float*)d_in[8];
  const float* ob2 = (const float*)d_in[9];
  const float* l1w = (const float*)d_in[10];
  const float* l1b = (const float*)d_in[11];
  const float* muw = (const float*)d_in[12];
  const float* mub = (const float*)d_in[13];
  const float* sw1 = (const float*)d_in[14];
  const float* sb1 = (const float*)d_in[15];
  const float* sw2 = (const float*)d_in[16];
  const float* sb2 = (const float*)d_in[17];
  float* ws  = (float*)d_ws;
  float* out = (float*)d_out;

  hipFuncSetAttribute((const void*)odernn_main,
                      hipFuncAttributeMaxDynamicSharedMemorySize, SMEM_BYTES);

  prep_w<<<WS_TOT / 256, 256, 0, stream>>>(Wih, Whh, l1w, sw1, ws);
  odernn_main<<<256, NT, SMEM_BYTES, stream>>>(dt, x, bih, bhh, ow1, ob1, ow2, ob2,
                                               l1b, muw, mub, sb1, sw2, sb2, ws, out);
}